// Round 4
// baseline (516.855 us; speedup 1.0000x reference)
//
#include <hip/hip_runtime.h>

// 2-layer LSTM (B=2048,T=512,in=4,H=64) + FC + tanh. MFMA f16, layer-pipelined,
// 8 waves/block (2 waves/SIMD) with an LDS gate exchange.
//
// Grid = 256 blocks x 512 threads. Block owns MB=8 batches.
// M rows 0-7 = layer 0 @ step t; rows 8-15 = layer 1 @ step t-1 (pipeline skew).
// K stacked (7 chunks of 32): [x-pad | h0@W0 | h0@W1i | h1@W1h]; row-group
// zeros are applied with in-register cndmask selects on single-copy h buffers
// (both L0@t and L1@t-1 consume the SAME h0[t-1] -> one copy serves chunks 1-4).
// Wave w owns N-tiles {w, w+8} (14 MFMA/wave/round). Gate preacts go through a
// 4-buffer LDS exchange; each of the 512 lanes then owns exactly 2 cells
// (cell0 = L0, cell1 = L1) -> per-wave transcendental work is halved vs R3 and
// two waves/SIMD overlap MFMA / LDS / VALU.

#define HID 64
#define TSTEPS 512
#define MB 8
#define BLK 512
#define HSTR 72   // f16 words per h row (144 B: keeps ds_read_b128 16B-aligned)
#define GSTR 65   // f32 words per gate-buffer row (odd -> bank spread)

typedef _Float16 f16;
typedef _Float16 half8 __attribute__((ext_vector_type(8)));
typedef _Float16 half4 __attribute__((ext_vector_type(4)));
typedef float f32x4 __attribute__((ext_vector_type(4)));

__device__ __forceinline__ float sigf(float x) {
    const float e = __expf(-x);                    // x<<0: e=inf, rcp->0: safe
    return __builtin_amdgcn_rcpf(1.0f + e);
}
__device__ __forceinline__ float tanh_safe(float x) {
    const float ax = fabsf(x);
    const float e  = __expf(-2.0f * ax);           // non-positive arg: no overflow
    const float t  = (1.0f - e) * __builtin_amdgcn_rcpf(1.0f + e);
    return copysignf(t, x);
}

__global__ __launch_bounds__(BLK, 2) void lstm_mfma(
    const float* __restrict__ x,      // (2048, 512, 4)
    const float* __restrict__ w_ih0,  // (256, 4)
    const float* __restrict__ w_hh0,  // (256, 64)
    const float* __restrict__ b_ih0,  // (256,)
    const float* __restrict__ b_hh0,  // (256,)
    const float* __restrict__ w_ih1,  // (256, 64)
    const float* __restrict__ w_hh1,  // (256, 64)
    const float* __restrict__ b_ih1,  // (256,)
    const float* __restrict__ b_hh1,  // (256,)
    const float* __restrict__ fc_w,   // (64, 64)
    const float* __restrict__ fc_b,   // (64,)
    float* __restrict__ out)          // (2048, 64)
{
    __shared__ f16   xs[TSTEPS * MB * 4];   // [t][m][4]  32 KB
    __shared__ f16   h0s[2][8 * HSTR];      // h0, single copy, parity dbuf
    __shared__ f16   h1s[2][8 * HSTR];      // h1
    __shared__ float gbuf[4][16 * GSTR];    // gate exchange: [gate][row][u]

    const int tid  = threadIdx.x;
    const int w    = tid >> 6;        // wave 0..7
    const int l    = tid & 63;
    const int quad = l >> 4;          // 0..3
    const int l15  = l & 15;
    const int b0   = blockIdx.x * MB;

    // ---- stage x into LDS as f16 ----
    for (int it = tid; it < MB * TSTEPS; it += BLK) {
        const int m = it >> 9;        // 0..7
        const int t = it & 511;
        const float4 v = *((const float4*)x + (size_t)(b0 + m) * TSTEPS + t);
        *(half4*)(xs + (t * MB + m) * 4) =
            (half4){ (f16)v.x, (f16)v.y, (f16)v.z, (f16)v.w };
    }
    // zero h state (both parities)
    for (int it = tid; it < 8 * HSTR; it += BLK) {
        h0s[0][it] = (f16)0.f; h0s[1][it] = (f16)0.f;
        h1s[0][it] = (f16)0.f; h1s[1][it] = (f16)0.f;
    }

    // ---- B-fragments: 2 N-tiles x 7 K-chunks, held in regs all 513 rounds ----
    // B[k=quad*8+j][n=tile*16+l15]; tiles {w, w+8}.
    half8 Bf[2][7];
    float biasr[2];
    #pragma unroll
    for (int ti = 0; ti < 2; ++ti) {
        const int n = (w + 8 * ti) * 16 + l15;
        half8 pz = { (f16)0.f,(f16)0.f,(f16)0.f,(f16)0.f,
                     (f16)0.f,(f16)0.f,(f16)0.f,(f16)0.f };
        if (quad == 0) {
            const float4 v = *(const float4*)(w_ih0 + n * 4);
            pz[0] = (f16)v.x; pz[1] = (f16)v.y; pz[2] = (f16)v.z; pz[3] = (f16)v.w;
        }
        Bf[ti][0] = pz;
        #pragma unroll
        for (int ks = 0; ks < 2; ++ks) {
            const int ko = ks * 32 + quad * 8;
            const float4 a = *(const float4*)(w_hh0 + n * HID + ko);
            const float4 b = *(const float4*)(w_hh0 + n * HID + ko + 4);
            Bf[ti][1 + ks] = (half8){ (f16)a.x,(f16)a.y,(f16)a.z,(f16)a.w,
                                      (f16)b.x,(f16)b.y,(f16)b.z,(f16)b.w };
            const float4 c = *(const float4*)(w_ih1 + n * HID + ko);
            const float4 d = *(const float4*)(w_ih1 + n * HID + ko + 4);
            Bf[ti][3 + ks] = (half8){ (f16)c.x,(f16)c.y,(f16)c.z,(f16)c.w,
                                      (f16)d.x,(f16)d.y,(f16)d.z,(f16)d.w };
            const float4 e = *(const float4*)(w_hh1 + n * HID + ko);
            const float4 h = *(const float4*)(w_hh1 + n * HID + ko + 4);
            Bf[ti][5 + ks] = (half8){ (f16)e.x,(f16)e.y,(f16)e.z,(f16)e.w,
                                      (f16)h.x,(f16)h.y,(f16)h.z,(f16)h.w };
        }
        // C/D rows quad*4+rr: quads 0-1 = layer-0 cells, quads 2-3 = layer-1
        biasr[ti] = (quad < 2) ? (b_ih0[n] + b_hh0[n]) : (b_ih1[n] + b_hh1[n]);
    }

    const int gA  = w >> 2;             // gate buffer for tile w   (0 or 1)
    const int gB  = gA + 2;             // gate buffer for tile w+8 (2 or 3)
    const int uu  = (w & 3) * 16 + l15; // unit column (same for both tiles)
    const int urd = tid & 63;           // activation-phase unit
    const int mrd = tid >> 6;           // activation-phase batch (== wave)
    float c0 = 0.f, c1 = 0.f;           // cell state: c0=L0 cell, c1=L1 cell
    __syncthreads();

    #pragma unroll 1
    for (int r = 0; r <= TSTEPS; ++r) {   // 513 rounds (pipeline fill/drain)
        const int pr = r & 1;
        const int pv = pr ^ 1;
        const int t  = (r < TSTEPS) ? r : (TSTEPS - 1);  // r=512 L0: garbage, unread

        // ---- A-fragments: single-copy h + cndmask row-group zeroing ----
        const bool lo8  = (l15 < 8);
        const int  hoff = (l15 & 7) * HSTR + quad * 8;
        const half8 h0lo = *(const half8*)(h0s[pv] + hoff);
        const half8 h0hi = *(const half8*)(h0s[pv] + hoff + 32);
        const half8 h1lo = *(const half8*)(h1s[pv] + hoff);
        const half8 h1hi = *(const half8*)(h1s[pv] + hoff + 32);
        const half8 z = { (f16)0.f,(f16)0.f,(f16)0.f,(f16)0.f,
                          (f16)0.f,(f16)0.f,(f16)0.f,(f16)0.f };
        const half8 A1 = lo8 ? h0lo : z;   // chunk1: h0 for L0 rows
        const half8 A2 = lo8 ? h0hi : z;   // chunk2
        const half8 A3 = lo8 ? z : h0lo;   // chunk3: same h0, L1 rows
        const half8 A4 = lo8 ? z : h0hi;   // chunk4
        const half8 A5 = lo8 ? z : h1lo;   // chunk5: h1, L1 rows
        const half8 A6 = lo8 ? z : h1hi;   // chunk6

        const half4 xv = *(const half4*)(xs + (t * MB + (l15 & 7)) * 4);
        half8 ax = z;
        if (quad == 0 && lo8) {
            ax[0] = xv[0]; ax[1] = xv[1]; ax[2] = xv[2]; ax[3] = xv[3];
        }

        // ---- 14 MFMA: 2 N-tiles x 7 K-chunks ----
        f32x4 g0, g1;
        {
            f32x4 acc = { biasr[0], biasr[0], biasr[0], biasr[0] };
            acc = __builtin_amdgcn_mfma_f32_16x16x32_f16(ax, Bf[0][0], acc, 0, 0, 0);
            acc = __builtin_amdgcn_mfma_f32_16x16x32_f16(A1, Bf[0][1], acc, 0, 0, 0);
            acc = __builtin_amdgcn_mfma_f32_16x16x32_f16(A2, Bf[0][2], acc, 0, 0, 0);
            acc = __builtin_amdgcn_mfma_f32_16x16x32_f16(A3, Bf[0][3], acc, 0, 0, 0);
            acc = __builtin_amdgcn_mfma_f32_16x16x32_f16(A4, Bf[0][4], acc, 0, 0, 0);
            acc = __builtin_amdgcn_mfma_f32_16x16x32_f16(A5, Bf[0][5], acc, 0, 0, 0);
            g0  = __builtin_amdgcn_mfma_f32_16x16x32_f16(A6, Bf[0][6], acc, 0, 0, 0);
        }
        {
            f32x4 acc = { biasr[1], biasr[1], biasr[1], biasr[1] };
            acc = __builtin_amdgcn_mfma_f32_16x16x32_f16(ax, Bf[1][0], acc, 0, 0, 0);
            acc = __builtin_amdgcn_mfma_f32_16x16x32_f16(A1, Bf[1][1], acc, 0, 0, 0);
            acc = __builtin_amdgcn_mfma_f32_16x16x32_f16(A2, Bf[1][2], acc, 0, 0, 0);
            acc = __builtin_amdgcn_mfma_f32_16x16x32_f16(A3, Bf[1][3], acc, 0, 0, 0);
            acc = __builtin_amdgcn_mfma_f32_16x16x32_f16(A4, Bf[1][4], acc, 0, 0, 0);
            acc = __builtin_amdgcn_mfma_f32_16x16x32_f16(A5, Bf[1][5], acc, 0, 0, 0);
            g1  = __builtin_amdgcn_mfma_f32_16x16x32_f16(A6, Bf[1][6], acc, 0, 0, 0);
        }

        // ---- scatter gate preacts to exchange buffers ----
        #pragma unroll
        for (int rr = 0; rr < 4; ++rr) {
            const int row = quad * 4 + rr;       // C/D row = quad*4 + reg
            gbuf[gA][row * GSTR + uu] = g0[rr];
            gbuf[gB][row * GSTR + uu] = g1[rr];
        }
        __syncthreads();

        // ---- activations: each lane owns cell0 (L0) + cell1 (L1) ----
        {
            const int o0 = mrd * GSTR + urd;         // L0 cell (row mrd)
            const int o1 = (8 + mrd) * GSTR + urd;   // L1 cell (row 8+mrd)
            const float gi = sigf(gbuf[0][o0]);
            const float gf = sigf(gbuf[1][o0]);
            const float gg = tanh_safe(gbuf[2][o0]);
            const float go = sigf(gbuf[3][o0]);
            c0 = gf * c0 + gi * gg;
            h0s[pr][mrd * HSTR + urd] = (f16)(go * tanh_safe(c0));

            const float gi1 = sigf(gbuf[0][o1]);
            const float gf1 = sigf(gbuf[1][o1]);
            const float gg1 = tanh_safe(gbuf[2][o1]);
            const float go1 = sigf(gbuf[3][o1]);
            const float keep = (r == 0) ? 0.f : 1.f;   // round 0: L1 computes step -1
            c1 = keep * (gf1 * c1 + gi1 * gg1);
            h1s[pr][mrd * HSTR + urd] = (f16)(keep * go1 * tanh_safe(c1));
        }
        __syncthreads();
    }

    // ---- epilogue: round 512 (parity 0) wrote h1 of step 511 ----
    {
        const int v = tid & 63;
        const int m = tid >> 6;
        float a = fc_b[v];
        const f16* hp = h1s[0] + m * HSTR;
        const float4* wp = (const float4*)(fc_w + v * HID);
        #pragma unroll
        for (int kk = 0; kk < HID / 4; ++kk) {
            const float4 wv = wp[kk];
            a += (float)hp[kk * 4 + 0] * wv.x + (float)hp[kk * 4 + 1] * wv.y
               + (float)hp[kk * 4 + 2] * wv.z + (float)hp[kk * 4 + 3] * wv.w;
        }
        out[(size_t)(b0 + m) * HID + v] = tanh_safe(a);
    }
}

extern "C" void kernel_launch(void* const* d_in, const int* in_sizes, int n_in,
                              void* d_out, int out_size, void* d_ws, size_t ws_size,
                              hipStream_t stream) {
    const float* x     = (const float*)d_in[0];
    const float* w_ih0 = (const float*)d_in[1];
    const float* w_hh0 = (const float*)d_in[2];
    const float* b_ih0 = (const float*)d_in[3];
    const float* b_hh0 = (const float*)d_in[4];
    const float* w_ih1 = (const float*)d_in[5];
    const float* w_hh1 = (const float*)d_in[6];
    const float* b_ih1 = (const float*)d_in[7];
    const float* b_hh1 = (const float*)d_in[8];
    const float* fc_w  = (const float*)d_in[9];
    const float* fc_b  = (const float*)d_in[10];
    float* out = (float*)d_out;

    const int B = in_sizes[0] / (TSTEPS * 4);   // 2048
    lstm_mfma<<<dim3(B / MB), dim3(BLK), 0, stream>>>(
        x, w_ih0, w_hh0, b_ih0, b_hh0, w_ih1, w_hh1, b_ih1, b_hh1, fc_w, fc_b, out);
}

// Round 5
// 439.737 us; speedup vs baseline: 1.1754x; 1.1754x over previous
//
#include <hip/hip_runtime.h>

// 2-layer LSTM (B=2048,T=512,in=4,H=64) + FC + tanh. MFMA f16 with WAVE
// SPECIALIZATION: waves 0-3 = layer-0 group, waves 4-7 = layer-1 group
// (one of each per SIMD) so MFMA and activations of different layers overlap
// on different pipes instead of phase-locking at barriers.
//
// Per round r (514 rounds, L1 lags L0 by 2 steps):
//   Seg A: L0-waves MFMA step r (needs h0(r-1))   | L1-waves act step r-2
//   Seg B: L0-waves act step r  (write h0(r))     | L1-waves MFMA step r-1
//                                                   (needs h0(r-1), h1(r-2))
// MFMA instr count identical to the fused form (L0 16 tiles x 3 chunks = 48,
// L1 16 x 4 = 64). M rows 8-15 duplicate batches 0-7 (outputs discarded) ->
// no cndmask zeroing anywhere. Wave owns N-tiles {w,w+4,w+8,w+12} = all 4
// gates of units [w*16,w*16+16) -> gate scatter is 4x ds_write_b128, act read
// is 2x ds_read_b128 per lane. log2e prefolded into weights/biases: sigmoid =
// exp2+add+rcp, tanh = exp2+add+rcp+fma (overflow-safe: inf -> rcp -> 0).

#define HID 64
#define TSTEPS 512
#define MB 8
#define BLK 512
#define HSTR 72   // f16 words per h row (144 B: 16B-aligned b128 reads)
#define LOG2E  1.4426950408889634f
#define LOG2E2 2.8853900817779268f

typedef _Float16 f16;
typedef _Float16 half8 __attribute__((ext_vector_type(8)));
typedef _Float16 half4 __attribute__((ext_vector_type(4)));
typedef float f32x4 __attribute__((ext_vector_type(4)));

__device__ __forceinline__ float sig2(float y) {   // sigmoid(x), y = x*log2e
    return __builtin_amdgcn_rcpf(1.0f + __builtin_amdgcn_exp2f(-y));
}
__device__ __forceinline__ float tanh2(float y) {  // tanh(x), y = x*2*log2e
    return fmaf(2.0f, __builtin_amdgcn_rcpf(1.0f + __builtin_amdgcn_exp2f(-y)), -1.0f);
}

__global__ __launch_bounds__(BLK, 2) void lstm_mfma(
    const float* __restrict__ x,      // (2048, 512, 4)
    const float* __restrict__ w_ih0,  // (256, 4)
    const float* __restrict__ w_hh0,  // (256, 64)
    const float* __restrict__ b_ih0,  // (256,)
    const float* __restrict__ b_hh0,  // (256,)
    const float* __restrict__ w_ih1,  // (256, 64)
    const float* __restrict__ w_hh1,  // (256, 64)
    const float* __restrict__ b_ih1,  // (256,)
    const float* __restrict__ b_hh1,  // (256,)
    const float* __restrict__ fc_w,   // (64, 64)
    const float* __restrict__ fc_b,   // (64,)
    float* __restrict__ out)          // (2048, 64)
{
    __shared__ f16 xs[TSTEPS * MB * 4];                 // 32 KB
    __shared__ f16 h0s[2][MB * HSTR];                   // h0, parity dbuf
    __shared__ f16 h1s[MB * HSTR];                      // h1, single buffer
    __shared__ __align__(16) float gb0[MB * 64 * 4];    // L0 gates [m][u][g] 8 KB
    __shared__ __align__(16) float gb1[MB * 64 * 4];    // L1 gates 8 KB

    const int tid  = threadIdx.x;
    const int w    = tid >> 6;        // wave 0..7
    const int l    = tid & 63;
    const int quad = l >> 4;
    const int l15  = l & 15;
    const int wl   = w & 3;           // wave id within group
    const bool isL0 = (w < 4);
    const int b0   = blockIdx.x * MB;

    // ---- stage x into LDS as f16 ----
    for (int it = tid; it < MB * TSTEPS; it += BLK) {
        const int m = it >> 9;
        const int t = it & 511;
        const float4 v = *((const float4*)x + (size_t)(b0 + m) * TSTEPS + t);
        *(half4*)(xs + (t * MB + m) * 4) =
            (half4){ (f16)v.x, (f16)v.y, (f16)v.z, (f16)v.w };
    }
    // zero h state and gb1 (gb1 is read in round 0/1 before first real write)
    for (int it = tid; it < MB * HSTR; it += BLK) {
        h0s[0][it] = (f16)0.f; h0s[1][it] = (f16)0.f; h1s[it] = (f16)0.f;
    }
    for (int it = tid; it < MB * 64 * 4; it += BLK) { gb0[it] = 0.f; gb1[it] = 0.f; }

    // ---- B-fragments: 4 N-tiles x 4 K-chunks (L0 uses 3), prescaled by log2e ----
    // Wave owns tiles {wl, wl+4, wl+8, wl+12} -> tile ti == gate ti of units
    // uu = wl*16 + l15. B[k=quad*8+j][n = (wl+4*ti)*16 + l15].
    half8 Bf[4][4];
    float biasr[4];
    const half8 Z = { (f16)0.f,(f16)0.f,(f16)0.f,(f16)0.f,
                      (f16)0.f,(f16)0.f,(f16)0.f,(f16)0.f };
    #pragma unroll
    for (int ti = 0; ti < 4; ++ti) {
        const int n = (wl + 4 * ti) * 16 + l15;
        const float sc = (ti == 2) ? LOG2E2 : LOG2E;   // g-gate feeds tanh
        if (isL0) {
            biasr[ti] = (b_ih0[n] + b_hh0[n]) * sc;
            half8 pz = Z;
            if (quad == 0) {
                const float4 v = *(const float4*)(w_ih0 + n * 4);
                pz[0] = (f16)(v.x * sc); pz[1] = (f16)(v.y * sc);
                pz[2] = (f16)(v.z * sc); pz[3] = (f16)(v.w * sc);
            }
            Bf[ti][0] = pz;                 // chunk0: x-proj (K rows 4..31 zero)
            #pragma unroll
            for (int ks = 0; ks < 2; ++ks) {
                const int ko = ks * 32 + quad * 8;
                const float4 a = *(const float4*)(w_hh0 + n * HID + ko);
                const float4 b = *(const float4*)(w_hh0 + n * HID + ko + 4);
                Bf[ti][1 + ks] = (half8){
                    (f16)(a.x*sc),(f16)(a.y*sc),(f16)(a.z*sc),(f16)(a.w*sc),
                    (f16)(b.x*sc),(f16)(b.y*sc),(f16)(b.z*sc),(f16)(b.w*sc) };
            }
            Bf[ti][3] = Z;                  // unused by L0
        } else {
            biasr[ti] = (b_ih1[n] + b_hh1[n]) * sc;
            #pragma unroll
            for (int ks = 0; ks < 2; ++ks) {
                const int ko = ks * 32 + quad * 8;
                const float4 a = *(const float4*)(w_ih1 + n * HID + ko);
                const float4 b = *(const float4*)(w_ih1 + n * HID + ko + 4);
                Bf[ti][ks] = (half8){       // chunks 0-1: h0 @ W1i
                    (f16)(a.x*sc),(f16)(a.y*sc),(f16)(a.z*sc),(f16)(a.w*sc),
                    (f16)(b.x*sc),(f16)(b.y*sc),(f16)(b.z*sc),(f16)(b.w*sc) };
                const float4 c = *(const float4*)(w_hh1 + n * HID + ko);
                const float4 d = *(const float4*)(w_hh1 + n * HID + ko + 4);
                Bf[ti][2 + ks] = (half8){   // chunks 2-3: h1 @ W1h
                    (f16)(c.x*sc),(f16)(c.y*sc),(f16)(c.z*sc),(f16)(c.w*sc),
                    (f16)(d.x*sc),(f16)(d.y*sc),(f16)(d.z*sc),(f16)(d.w*sc) };
            }
        }
    }

    const int uu = wl * 16 + l15;       // unit base for gate scatter
    float cA = 0.f, cB = 0.f;           // cell state for cells (wl, l), (wl+4, l)
    __syncthreads();

    #pragma unroll 1
    for (int r = 0; r < TSTEPS + 2; ++r) {
        const int pr = r & 1;
        const int pv = pr ^ 1;

        // ================= segment A =================
        if (isL0) {
            // L0 MFMA step r: [x | h0(r-1)] -> gates, scatter to gb0
            const int t = (r < TSTEPS) ? r : (TSTEPS - 1);
            const half4 xv = *(const half4*)(xs + (t * MB + (l15 & 7)) * 4);
            half8 ax = Z;
            if (quad == 0) { ax[0]=xv[0]; ax[1]=xv[1]; ax[2]=xv[2]; ax[3]=xv[3]; }
            const int hb = (l15 & 7) * HSTR + quad * 8;   // rows 8-15 dup 0-7
            const half8 A1 = *(const half8*)(h0s[pv] + hb);
            const half8 A2 = *(const half8*)(h0s[pv] + hb + 32);
            f32x4 g[4];
            #pragma unroll
            for (int ti = 0; ti < 4; ++ti) {
                f32x4 acc = { biasr[ti], biasr[ti], biasr[ti], biasr[ti] };
                acc   = __builtin_amdgcn_mfma_f32_16x16x32_f16(ax, Bf[ti][0], acc, 0, 0, 0);
                acc   = __builtin_amdgcn_mfma_f32_16x16x32_f16(A1, Bf[ti][1], acc, 0, 0, 0);
                g[ti] = __builtin_amdgcn_mfma_f32_16x16x32_f16(A2, Bf[ti][2], acc, 0, 0, 0);
            }
            if (quad < 2) {     // rows 0-7 real; 4 gates contiguous -> b128
                #pragma unroll
                for (int rr = 0; rr < 4; ++rr) {
                    *(float4*)(gb0 + (((quad * 4 + rr) * 64) + uu) * 4) =
                        make_float4(g[0][rr], g[1][rr], g[2][rr], g[3][rr]);
                }
            }
        } else {
            // L1 activations step r-2 (gates in gb1), write h1(r-2)
            const float keep = (r >= 2) ? 1.f : 0.f;
            const float4 gv0 = *(const float4*)(gb1 + ((wl * 64) + l) * 4);
            const float4 gv1 = *(const float4*)(gb1 + (((wl + 4) * 64) + l) * 4);
            {
                const float gi = sig2(gv0.x), gf = sig2(gv0.y);
                const float gg = tanh2(gv0.z), go = sig2(gv0.w);
                cA = keep * (gf * cA + gi * gg);
                h1s[wl * HSTR + l] = (f16)(keep * go * tanh2(cA * LOG2E2));
            }
            {
                const float gi = sig2(gv1.x), gf = sig2(gv1.y);
                const float gg = tanh2(gv1.z), go = sig2(gv1.w);
                cB = keep * (gf * cB + gi * gg);
                h1s[(wl + 4) * HSTR + l] = (f16)(keep * go * tanh2(cB * LOG2E2));
            }
        }
        __syncthreads();

        // ================= segment B =================
        if (isL0) {
            // L0 activations step r (gates in gb0), write h0(r) -> parity pr
            const float4 gv0 = *(const float4*)(gb0 + ((wl * 64) + l) * 4);
            const float4 gv1 = *(const float4*)(gb0 + (((wl + 4) * 64) + l) * 4);
            {
                const float gi = sig2(gv0.x), gf = sig2(gv0.y);
                const float gg = tanh2(gv0.z), go = sig2(gv0.w);
                cA = gf * cA + gi * gg;
                h0s[pr][wl * HSTR + l] = (f16)(go * tanh2(cA * LOG2E2));
            }
            {
                const float gi = sig2(gv1.x), gf = sig2(gv1.y);
                const float gg = tanh2(gv1.z), go = sig2(gv1.w);
                cB = gf * cB + gi * gg;
                h0s[pr][(wl + 4) * HSTR + l] = (f16)(go * tanh2(cB * LOG2E2));
            }
        } else {
            // L1 MFMA step r-1: [h0(r-1) | h1(r-2)] -> gates, scatter to gb1
            const int hb = (l15 & 7) * HSTR + quad * 8;
            const half8 A1 = *(const half8*)(h0s[pv] + hb);   // h0(r-1)
            const half8 A2 = *(const half8*)(h0s[pv] + hb + 32);
            const half8 A3 = *(const half8*)(h1s + hb);       // h1(r-2)
            const half8 A4 = *(const half8*)(h1s + hb + 32);
            f32x4 g[4];
            #pragma unroll
            for (int ti = 0; ti < 4; ++ti) {
                f32x4 acc = { biasr[ti], biasr[ti], biasr[ti], biasr[ti] };
                acc   = __builtin_amdgcn_mfma_f32_16x16x32_f16(A1, Bf[ti][0], acc, 0, 0, 0);
                acc   = __builtin_amdgcn_mfma_f32_16x16x32_f16(A2, Bf[ti][1], acc, 0, 0, 0);
                acc   = __builtin_amdgcn_mfma_f32_16x16x32_f16(A3, Bf[ti][2], acc, 0, 0, 0);
                g[ti] = __builtin_amdgcn_mfma_f32_16x16x32_f16(A4, Bf[ti][3], acc, 0, 0, 0);
            }
            if (quad < 2) {
                #pragma unroll
                for (int rr = 0; rr < 4; ++rr) {
                    *(float4*)(gb1 + (((quad * 4 + rr) * 64) + uu) * 4) =
                        make_float4(g[0][rr], g[1][rr], g[2][rr], g[3][rr]);
                }
            }
        }
        __syncthreads();
    }

    // ---- epilogue: h1s holds h1(511). out[b][v] = tanh(h1 . fc_w[v] + fc_b[v]) ----
    {
        const int v = tid & 63;
        const int m = tid >> 6;
        float a = fc_b[v];
        const f16* hp = h1s + m * HSTR;
        const float4* wp = (const float4*)(fc_w + v * HID);
        #pragma unroll
        for (int kk = 0; kk < HID / 4; ++kk) {
            const float4 wv = wp[kk];
            a += (float)hp[kk * 4 + 0] * wv.x + (float)hp[kk * 4 + 1] * wv.y
               + (float)hp[kk * 4 + 2] * wv.z + (float)hp[kk * 4 + 3] * wv.w;
        }
        out[(size_t)(b0 + m) * HID + v] = tanh2(a * LOG2E2);
    }
}

extern "C" void kernel_launch(void* const* d_in, const int* in_sizes, int n_in,
                              void* d_out, int out_size, void* d_ws, size_t ws_size,
                              hipStream_t stream) {
    const float* x     = (const float*)d_in[0];
    const float* w_ih0 = (const float*)d_in[1];
    const float* w_hh0 = (const float*)d_in[2];
    const float* b_ih0 = (const float*)d_in[3];
    const float* b_hh0 = (const float*)d_in[4];
    const float* w_ih1 = (const float*)d_in[5];
    const float* w_hh1 = (const float*)d_in[6];
    const float* b_ih1 = (const float*)d_in[7];
    const float* b_hh1 = (const float*)d_in[8];
    const float* fc_w  = (const float*)d_in[9];
    const float* fc_b  = (const float*)d_in[10];
    float* out = (float*)d_out;

    const int B = in_sizes[0] / (TSTEPS * 4);   // 2048
    lstm_mfma<<<dim3(B / MB), dim3(BLK), 0, stream>>>(
        x, w_ih0, w_hh0, b_ih0, b_hh0, w_ih1, w_hh1, b_ih1, b_hh1, fc_w, fc_b, out);
}

// Round 6
// 381.724 us; speedup vs baseline: 1.3540x; 1.1520x over previous
//
#include <hip/hip_runtime.h>

// 2-layer LSTM (B=2048,T=512,in=4,H=64) + FC + tanh. MFMA f16, wave-specialized,
// ONE barrier per round, gates never leave registers.
//
// Grid 256 x 512 threads. Waves 0-3 = L0 group, waves 4-7 = L1 group (one of
// each per SIMD). Wave wl owns N-tiles {wl,wl+4,wl+8,wl+12} = ALL FOUR gates
// of units [wl*16, wl*16+16) -> MFMA C/D has i,f,g,o of cell (m,u) in the same
// lane (g[0..3][rr]); no LDS gate exchange. M rows 8-15 duplicate batches 0-7,
// so quads 0-1 own rr{0,1} and quads 2-3 own rr{2,3}: 2 real cells/lane.
//
// Round r (r = 0..512):
//   L0 waves (r<512): MFMA step r [x(r), h0(r-1)@pv] -> act -> h0(r)@pr
//   L1 waves:         MFMA step r-1 [h0(r-1)@pv, h1(r-2)@pr] -> act -> h1(r-1)@pv
//   one __syncthreads. All read/write parities differ from concurrent writes,
//   and cross-round reuse is separated by exactly one barrier.
// log2e prefolded into weights/biases: sigmoid = exp2+add+rcp; tanh = +fma.

#define HID 64
#define TSTEPS 512
#define MB 8
#define BLK 512
#define HSTR 72   // f16 words per h row (144 B: 16B-aligned b128 reads)
#define LOG2E  1.4426950408889634f
#define LOG2E2 2.8853900817779268f

typedef _Float16 f16;
typedef _Float16 half8 __attribute__((ext_vector_type(8)));
typedef _Float16 half4 __attribute__((ext_vector_type(4)));
typedef float f32x4 __attribute__((ext_vector_type(4)));

__device__ __forceinline__ float sig2(float y) {   // sigmoid(x), y = x*log2e
    return __builtin_amdgcn_rcpf(1.0f + __builtin_amdgcn_exp2f(-y));
}
__device__ __forceinline__ float tanh2(float y) {  // tanh(x), y = x*2*log2e
    return fmaf(2.0f, __builtin_amdgcn_rcpf(1.0f + __builtin_amdgcn_exp2f(-y)), -1.0f);
}

__global__ __launch_bounds__(BLK, 2) void lstm_mfma(
    const float* __restrict__ x,      // (2048, 512, 4)
    const float* __restrict__ w_ih0,  // (256, 4)
    const float* __restrict__ w_hh0,  // (256, 64)
    const float* __restrict__ b_ih0,  // (256,)
    const float* __restrict__ b_hh0,  // (256,)
    const float* __restrict__ w_ih1,  // (256, 64)
    const float* __restrict__ w_hh1,  // (256, 64)
    const float* __restrict__ b_ih1,  // (256,)
    const float* __restrict__ b_hh1,  // (256,)
    const float* __restrict__ fc_w,   // (64, 64)
    const float* __restrict__ fc_b,   // (64,)
    float* __restrict__ out)          // (2048, 64)
{
    __shared__ f16 xs[TSTEPS * MB * 4];     // 32 KB
    __shared__ f16 h0s[2][MB * HSTR];       // parity dbuf
    __shared__ f16 h1s[2][MB * HSTR];       // parity dbuf

    const int tid  = threadIdx.x;
    const int w    = tid >> 6;        // wave 0..7
    const int l    = tid & 63;
    const int quad = l >> 4;
    const int l15  = l & 15;
    const int wl   = w & 3;
    const bool isL0 = (w < 4);
    const int b0   = blockIdx.x * MB;

    // ---- stage x into LDS as f16 ----
    for (int it = tid; it < MB * TSTEPS; it += BLK) {
        const int m = it >> 9;
        const int t = it & 511;
        const float4 v = *((const float4*)x + (size_t)(b0 + m) * TSTEPS + t);
        *(half4*)(xs + (t * MB + m) * 4) =
            (half4){ (f16)v.x, (f16)v.y, (f16)v.z, (f16)v.w };
    }
    for (int it = tid; it < MB * HSTR; it += BLK) {
        h0s[0][it] = (f16)0.f; h0s[1][it] = (f16)0.f;
        h1s[0][it] = (f16)0.f; h1s[1][it] = (f16)0.f;
    }

    // ---- B-fragments: 4 N-tiles x up-to-4 K-chunks, prescaled by log2e ----
    // B[k=quad*8+j][n=(wl+4*ti)*16+l15]; tile ti == gate ti of units wl*16+l15.
    // L0: [0]=x-proj(pad), [1-2]=w_hh0, [3]=Z.  L1: [0-1]=w_ih1, [2-3]=w_hh1.
    half8 Bf[4][4];
    float biasr[4];
    const half8 Z = { (f16)0.f,(f16)0.f,(f16)0.f,(f16)0.f,
                      (f16)0.f,(f16)0.f,(f16)0.f,(f16)0.f };
    #pragma unroll
    for (int ti = 0; ti < 4; ++ti) {
        const int n = (wl + 4 * ti) * 16 + l15;
        const float sc = (ti == 2) ? LOG2E2 : LOG2E;   // g-gate feeds tanh2
        if (isL0) {
            biasr[ti] = (b_ih0[n] + b_hh0[n]) * sc;
            half8 pz = Z;
            if (quad == 0) {
                const float4 v = *(const float4*)(w_ih0 + n * 4);
                pz[0] = (f16)(v.x * sc); pz[1] = (f16)(v.y * sc);
                pz[2] = (f16)(v.z * sc); pz[3] = (f16)(v.w * sc);
            }
            Bf[ti][0] = pz;
            #pragma unroll
            for (int ks = 0; ks < 2; ++ks) {
                const int ko = ks * 32 + quad * 8;
                const float4 a = *(const float4*)(w_hh0 + n * HID + ko);
                const float4 b = *(const float4*)(w_hh0 + n * HID + ko + 4);
                Bf[ti][1 + ks] = (half8){
                    (f16)(a.x*sc),(f16)(a.y*sc),(f16)(a.z*sc),(f16)(a.w*sc),
                    (f16)(b.x*sc),(f16)(b.y*sc),(f16)(b.z*sc),(f16)(b.w*sc) };
            }
            Bf[ti][3] = Z;
        } else {
            biasr[ti] = (b_ih1[n] + b_hh1[n]) * sc;
            #pragma unroll
            for (int ks = 0; ks < 2; ++ks) {
                const int ko = ks * 32 + quad * 8;
                const float4 a = *(const float4*)(w_ih1 + n * HID + ko);
                const float4 b = *(const float4*)(w_ih1 + n * HID + ko + 4);
                Bf[ti][ks] = (half8){
                    (f16)(a.x*sc),(f16)(a.y*sc),(f16)(a.z*sc),(f16)(a.w*sc),
                    (f16)(b.x*sc),(f16)(b.y*sc),(f16)(b.z*sc),(f16)(b.w*sc) };
                const float4 c = *(const float4*)(w_hh1 + n * HID + ko);
                const float4 d = *(const float4*)(w_hh1 + n * HID + ko + 4);
                Bf[ti][2 + ks] = (half8){
                    (f16)(c.x*sc),(f16)(c.y*sc),(f16)(c.z*sc),(f16)(c.w*sc),
                    (f16)(d.x*sc),(f16)(d.y*sc),(f16)(d.z*sc),(f16)(d.w*sc) };
            }
        }
    }

    // cell ownership: quads 0-1 own rr{0,1}, quads 2-3 own rr{2,3};
    // batch row = (quad&1)*4 + rr0 + j, unit = wl*16 + l15.
    const bool lo   = (quad < 2);
    const int  mrow = (quad & 1) * 4 + (lo ? 0 : 2);
    const int  uu   = wl * 16 + l15;
    const int  hb   = (l15 & 7) * HSTR + quad * 8;   // A-frag base (rows dup 8)
    float cst0 = 0.f, cst1 = 0.f;
    __syncthreads();

    #pragma unroll 1
    for (int r = 0; r <= TSTEPS; ++r) {
        const int pr = r & 1;
        const int pv = pr ^ 1;

        if (isL0) {
            if (r < TSTEPS) {
                // ---- L0 MFMA step r: [x | h0(r-1)@pv] ----
                const half4 xv = *(const half4*)(xs + (r * MB + (l15 & 7)) * 4);
                half8 ax = Z;
                if (quad == 0) { ax[0]=xv[0]; ax[1]=xv[1]; ax[2]=xv[2]; ax[3]=xv[3]; }
                const half8 A1 = *(const half8*)(h0s[pv] + hb);
                const half8 A2 = *(const half8*)(h0s[pv] + hb + 32);
                f32x4 g[4];
                #pragma unroll
                for (int ti = 0; ti < 4; ++ti) {
                    f32x4 acc = { biasr[ti], biasr[ti], biasr[ti], biasr[ti] };
                    acc   = __builtin_amdgcn_mfma_f32_16x16x32_f16(ax, Bf[ti][0], acc, 0, 0, 0);
                    acc   = __builtin_amdgcn_mfma_f32_16x16x32_f16(A1, Bf[ti][1], acc, 0, 0, 0);
                    g[ti] = __builtin_amdgcn_mfma_f32_16x16x32_f16(A2, Bf[ti][2], acc, 0, 0, 0);
                }
                // ---- L0 act, in-register; write h0(r)@pr ----
                #pragma unroll
                for (int j = 0; j < 2; ++j) {
                    const float pi = lo ? g[0][j] : g[0][2 + j];
                    const float pf = lo ? g[1][j] : g[1][2 + j];
                    const float pg = lo ? g[2][j] : g[2][2 + j];
                    const float po = lo ? g[3][j] : g[3][2 + j];
                    float& c = j ? cst1 : cst0;
                    c = sig2(pf) * c + sig2(pi) * tanh2(pg);
                    h0s[pr][(mrow + j) * HSTR + uu] =
                        (f16)(sig2(po) * tanh2(c * LOG2E2));
                }
            }
        } else {
            // ---- L1 MFMA step r-1: [h0(r-1)@pv | h1(r-2)@pr] ----
            const half8 A1 = *(const half8*)(h0s[pv] + hb);
            const half8 A2 = *(const half8*)(h0s[pv] + hb + 32);
            const half8 A3 = *(const half8*)(h1s[pr] + hb);
            const half8 A4 = *(const half8*)(h1s[pr] + hb + 32);
            f32x4 g[4];
            #pragma unroll
            for (int ti = 0; ti < 4; ++ti) {
                f32x4 acc = { biasr[ti], biasr[ti], biasr[ti], biasr[ti] };
                acc   = __builtin_amdgcn_mfma_f32_16x16x32_f16(A1, Bf[ti][0], acc, 0, 0, 0);
                acc   = __builtin_amdgcn_mfma_f32_16x16x32_f16(A2, Bf[ti][1], acc, 0, 0, 0);
                acc   = __builtin_amdgcn_mfma_f32_16x16x32_f16(A3, Bf[ti][2], acc, 0, 0, 0);
                g[ti] = __builtin_amdgcn_mfma_f32_16x16x32_f16(A4, Bf[ti][3], acc, 0, 0, 0);
            }
            // ---- L1 act; r==0 computes step -1 -> squash to zero ----
            const float keep = (r > 0) ? 1.f : 0.f;
            #pragma unroll
            for (int j = 0; j < 2; ++j) {
                const float pi = lo ? g[0][j] : g[0][2 + j];
                const float pf = lo ? g[1][j] : g[1][2 + j];
                const float pg = lo ? g[2][j] : g[2][2 + j];
                const float po = lo ? g[3][j] : g[3][2 + j];
                float& c = j ? cst1 : cst0;
                c = keep * (sig2(pf) * c + sig2(pi) * tanh2(pg));
                h1s[pv][(mrow + j) * HSTR + uu] =
                    (f16)(keep * sig2(po) * tanh2(c * LOG2E2));
            }
        }
        __syncthreads();
    }

    // ---- epilogue: h1(511) was written in round 512 to parity pv=1 ----
    {
        const int v = tid & 63;
        const int m = tid >> 6;
        float a = fc_b[v];
        const f16* hp = h1s[1] + m * HSTR;
        const float4* wp = (const float4*)(fc_w + v * HID);
        #pragma unroll
        for (int kk = 0; kk < HID / 4; ++kk) {
            const float4 wv = wp[kk];
            a += (float)hp[kk * 4 + 0] * wv.x + (float)hp[kk * 4 + 1] * wv.y
               + (float)hp[kk * 4 + 2] * wv.z + (float)hp[kk * 4 + 3] * wv.w;
        }
        out[(size_t)(b0 + m) * HID + v] = tanh2(a * LOG2E2);
    }
}

extern "C" void kernel_launch(void* const* d_in, const int* in_sizes, int n_in,
                              void* d_out, int out_size, void* d_ws, size_t ws_size,
                              hipStream_t stream) {
    const float* x     = (const float*)d_in[0];
    const float* w_ih0 = (const float*)d_in[1];
    const float* w_hh0 = (const float*)d_in[2];
    const float* b_ih0 = (const float*)d_in[3];
    const float* b_hh0 = (const float*)d_in[4];
    const float* w_ih1 = (const float*)d_in[5];
    const float* w_hh1 = (const float*)d_in[6];
    const float* b_ih1 = (const float*)d_in[7];
    const float* b_hh1 = (const float*)d_in[8];
    const float* fc_w  = (const float*)d_in[9];
    const float* fc_b  = (const float*)d_in[10];
    float* out = (float*)d_out;

    const int B = in_sizes[0] / (TSTEPS * 4);   // 2048
    lstm_mfma<<<dim3(B / MB), dim3(BLK), 0, stream>>>(
        x, w_ih0, w_hh0, b_ih0, b_hh0, w_ih1, w_hh1, b_ih1, b_hh1, fc_w, fc_b, out);
}